// Round 1
// baseline (257.034 us; speedup 1.0000x reference)
//
#include <hip/hip_runtime.h>
#include <hip/hip_bf16.h>
#include <cstdint>
#include <cstddef>

// TT-dense: y = relu(x @ M + b)
// x: [4096,4096] f32, M: TT(cores r=1,16,16,16,1, dims 8^4 x 8^4), out f32.
//
// Route: materialize M^T in bf16, convert x to bf16, one 4096^3 bf16 MFMA
// GEMM with fused bias+relu.
// History: R2 swizzle kills conflicts; R4 BK=64; R5 full-rate swizzle -> 0
//   conflicts, ~160us GEMM (m97-structure ceiling ~860 TF); R6 LDS-free GEMM
//   regressed; R7 split pre-work pipelining -> 268.7us total.
// R8: GEMM restructured to the 256^2 8-phase schedule (T1+T2+T3+T4+T5):
//   256x256 tile, BK=64, 8 waves, 128KB double-buffered LDS, granule-grain
//   prefetch with counted s_waitcnt vmcnt(6) (never 0 in main loop), raw
//   s_barrier phases, s_setprio around MFMA clusters. Rotation swizzle kept
//   (proven conflict-free). Target ~1550 TF -> ~90us GEMM.

#define GM 4096
#define GN 4096
#define GK 4096
#define NT (GK / 64)

typedef __attribute__((ext_vector_type(8))) short short8_t;
typedef __attribute__((ext_vector_type(4))) float float4_t;

__device__ __forceinline__ unsigned short f2bf(float f) {
  union { float f; uint32_t u; } v; v.f = f;
  uint32_t u = v.u;
  uint32_t r = (u + 0x7fffu + ((u >> 16) & 1u)) >> 16;  // RNE
  return (unsigned short)r;
}

// ---------------------------------------------------------------------------
// Kernel 1 (512 blocks, ~4us): merge core pairs.
// G01[a01][b01][r2] = sum_r1 core0[0,a0,b0,r1] * core1[r1,a1,b1,r2]
// G23t[r2][b23][a23] = sum_r3 core2[r2,a2,b2,r3] * core3[r3,a3,b3,0]
// ---------------------------------------------------------------------------
__global__ __launch_bounds__(256) void prep_kernel(
    const float* __restrict__ c0, const float* __restrict__ c1,
    const float* __restrict__ c2, const float* __restrict__ c3,
    float* __restrict__ G01, float* __restrict__ G23t) {
  int idx = blockIdx.x * 256 + threadIdx.x;  // 0..131071
  if (idx < 65536) {
    int r2 = idx & 15;
    int b01 = (idx >> 4) & 63;
    int a01 = idx >> 10;
    int a0 = a01 >> 3, a1 = a01 & 7, b0 = b01 >> 3, b1 = b01 & 7;
    float s = 0.f;
#pragma unroll
    for (int r1 = 0; r1 < 16; ++r1)
      s += c0[(a0 * 8 + b0) * 16 + r1] * c1[((r1 * 8 + a1) * 8 + b1) * 16 + r2];
    G01[idx] = s;
  } else {
    int t = idx - 65536;  // t = r2*4096 + b23*64 + a23
    int a23 = t & 63;
    int b23 = (t >> 6) & 63;
    int r2 = t >> 12;
    int a2 = a23 >> 3, a3 = a23 & 7, b2 = b23 >> 3, b3 = b23 & 7;
    float s = 0.f;
#pragma unroll
    for (int r3 = 0; r3 < 16; ++r3)
      s += c2[((r2 * 8 + a2) * 8 + b2) * 16 + r3] * c3[(r3 * 8 + a3) * 8 + b3];
    G23t[t] = s;
  }
}

// ---------------------------------------------------------------------------
// Kernel 2 (fused, mutually independent halves):
//  blocks [0,1024): Mt[n][k] = sum_r2 G01[a01][b01][r2] * G23t[r2][b23][a23]
//  blocks [1024, 9216): x f32 -> bf16 RNE, 8 elems/thread.
// ---------------------------------------------------------------------------
__global__ __launch_bounds__(256) void mt_convert(
    const float* __restrict__ G01, const float* __restrict__ G23t,
    unsigned short* __restrict__ Mt,
    const float* __restrict__ x, unsigned short* __restrict__ xb) {
  int bid = blockIdx.x;
  int tid = threadIdx.x;
  if (bid < 1024) {
    int a01 = bid >> 4;
    int g = bid & 15;  // b01 = g*4 + j

    float acc[4][16];
#pragma unroll
    for (int j = 0; j < 4; ++j)
#pragma unroll
      for (int i = 0; i < 16; ++i) acc[j][i] = 0.f;

    for (int r2 = 0; r2 < 16; ++r2) {
      float gv[4];
#pragma unroll
      for (int j = 0; j < 4; ++j)
        gv[j] = G01[(a01 * 64 + g * 4 + j) * 16 + r2];  // block-uniform
      const float* src = G23t + r2 * 4096 + tid * 16;   // 64B contiguous/lane
      float4_t v0 = *(const float4_t*)(src);
      float4_t v1 = *(const float4_t*)(src + 4);
      float4_t v2 = *(const float4_t*)(src + 8);
      float4_t v3 = *(const float4_t*)(src + 12);
#pragma unroll
      for (int j = 0; j < 4; ++j) {
#pragma unroll
        for (int l = 0; l < 4; ++l) {
          acc[j][l]      += gv[j] * v0[l];
          acc[j][4 + l]  += gv[j] * v1[l];
          acc[j][8 + l]  += gv[j] * v2[l];
          acc[j][12 + l] += gv[j] * v3[l];
        }
      }
    }

    int b23 = tid >> 2;
    int a23base = (tid & 3) * 16;
#pragma unroll
    for (int j = 0; j < 4; ++j) {
      short8_t o0, o1;
#pragma unroll
      for (int i = 0; i < 8; ++i) {
        o0[i] = (short)f2bf(acc[j][i]);
        o1[i] = (short)f2bf(acc[j][8 + i]);
      }
      size_t base = (size_t)((g * 4 + j) * 64 + b23) * GK + a01 * 64 + a23base;
      *(short8_t*)(Mt + base) = o0;
      *(short8_t*)(Mt + base + 8) = o1;
    }
  } else {
    int i = ((bid - 1024) * 256 + tid) * 8;
    float4_t a = *(const float4_t*)(x + i);
    float4_t b = *(const float4_t*)(x + i + 4);
    short8_t o;
    o[0] = (short)f2bf(a[0]); o[1] = (short)f2bf(a[1]);
    o[2] = (short)f2bf(a[2]); o[3] = (short)f2bf(a[3]);
    o[4] = (short)f2bf(b[0]); o[5] = (short)f2bf(b[1]);
    o[6] = (short)f2bf(b[2]); o[7] = (short)f2bf(b[3]);
    *(short8_t*)(xb + i) = o;
  }
}

// ---------------------------------------------------------------------------
// Kernel 3: C = relu(A @ Bt^T + bias). A:[M][K] bf16, Bt:[N][K] bf16.
//
// 256x256 tile, BK=64, 8 waves (2M x 4N), 512 threads, 128 KiB LDS
// (2 buffers x (A 32KB + B 32KB)). 4 phases per K-tile:
//   P0: ds_read B(all)+A m0-1 (12 reads) | issue (t+1).B1 | bar | 16 MFMA | bar
//   P1: ds_read A m2-3 (4)               | issue (t+2).B0 | bar | 16 MFMA | bar
//   P2: ds_read A m4-7 (8)               |                | bar | 16 MFMA |
//       lgkmcnt(0) (all buf[cur] reads done -> A overwrite legal) | bar
//   P3: issue (t+2).A0,A1                | bar | 16 MFMA | vmcnt(6) | bar
// vmcnt(6) = 3 granules (6 loads) in flight across the boundary; never 0 in
// the main loop (tail: vmcnt(0) at kt=NT-2). Granule overwrite of buf[cur] is
// only issued after a barrier that postdates completion of every wave's reads
// of that region (B after P0, A after P2's drain).
//
// LDS rotation swizzle (R5, 0 conflicts): row r chunk of k-half h stored at
// pos p=(h+r)&7; staging keeps lane-linear LDS dest (tid*16B) and permutes
// the global source k-offset. Row deltas of 16 keep r%8 fixed -> one base
// offset per matrix, ks=1 = base^32, frag m = +m*1024 (folds into ds_read
// immediate offsets).
//
// XCD swizzle: 256 blocks = 1/CU; each XCD gets a 4x8 region of the 16x16
// tile grid (bijective, 256%8==0).
// ---------------------------------------------------------------------------
__global__ __launch_bounds__(512, 2) void gemm_bias_relu(
    const unsigned short* __restrict__ A, const unsigned short* __restrict__ Bt,
    const float* __restrict__ bias, float* __restrict__ C) {
  extern __shared__ __align__(16) unsigned short lds[];

  const int tid = threadIdx.x;
  const int bswz = blockIdx.x;
  const int xcd = bswz & 7, li = bswz >> 3;
  const int row0 = ((xcd >> 1) * 4 + (li >> 3)) * 256;
  const int col0 = ((xcd & 1) * 8 + (li & 7)) * 256;
  const int wave = tid >> 6, lane = tid & 63;
  const int wm = wave >> 2, wn = wave & 3;
  const int half = lane >> 4, mrow = lane & 15;

  // Staging invariants: chunk c = q*512+tid; r=c>>3, p=c&7, h=(p-r)&7.
  // q=1 is exactly +64 rows (h unchanged since 64%8==0).
  const int r0 = tid >> 3, p0 = tid & 7, h0 = (p0 - r0) & 7;
  const unsigned short* Abase = A + (size_t)(row0 + r0) * GK + h0 * 8;
  const unsigned short* Bbase = Bt + (size_t)(col0 + r0) * GK + h0 * 8;
  const int dA = r0 * 64 + p0 * 8;   // shorts; wave-linear: = tid*16 bytes
  const int dB = dA + 16384;

#define GLD(SRC, DST)                                                  \
  __builtin_amdgcn_global_load_lds(                                    \
      (const __attribute__((address_space(1))) void*)(SRC),            \
      (__attribute__((address_space(3))) void*)(lds + (DST)), 16, 0, 0)
#define STAGE_A(G, KT, BUF)                                            \
  do {                                                                 \
    const unsigned short* s_ = Abase + (size_t)(G) * 128 * GK + (KT) * 64; \
    GLD(s_, (BUF) * 32768 + (G) * 8192 + dA);                          \
    GLD(s_ + (size_t)64 * GK, (BUF) * 32768 + (G) * 8192 + dA + 4096); \
  } while (0)
#define STAGE_B(G, KT, BUF)                                            \
  do {                                                                 \
    const unsigned short* s_ = Bbase + (size_t)(G) * 128 * GK + (KT) * 64; \
    GLD(s_, (BUF) * 32768 + (G) * 8192 + dB);                          \
    GLD(s_ + (size_t)64 * GK, (BUF) * 32768 + (G) * 8192 + dB + 4096); \
  } while (0)

  // Fragment read offsets (shorts). r%8 is m-invariant -> single base,
  // ks=1 flips rotation bit2 -> ^32 shorts; frag m adds m*1024.
  const int arow = wm * 128 + mrow;
  const int aoff0 = arow * 64 + ((half + arow) & 7) * 8;
  const int aoff1 = aoff0 ^ 32;
  const int brow = wn * 64 + mrow;
  const int boff0 = 16384 + brow * 64 + ((half + brow) & 7) * 8;
  const int boff1 = boff0 ^ 32;

  float4_t acc[8][4];
#pragma unroll
  for (int i = 0; i < 8; ++i)
#pragma unroll
    for (int n = 0; n < 4; ++n) acc[i][n] = (float4_t){0.f, 0.f, 0.f, 0.f};

  // Prologue: tile0 complete -> buf0; tile1 {B0,A0,A1} -> buf1 (g3 comes at
  // tile0.P0). vmcnt(6): tile0's 8 loads landed, 3 granules outstanding.
  STAGE_A(0, 0, 0); STAGE_A(1, 0, 0); STAGE_B(0, 0, 0); STAGE_B(1, 0, 0);
  STAGE_B(0, 1, 1); STAGE_A(0, 1, 1); STAGE_A(1, 1, 1);
  asm volatile("s_waitcnt vmcnt(6)" ::: "memory");
  __builtin_amdgcn_s_barrier();

#pragma unroll 2
  for (int kt = 0; kt < NT; ++kt) {
    const int cur = kt & 1;
    const int cb = cur * 32768;

    short8_t bfr[4][2], af01[2][2], af23[2][2], af45[2][2], af67[2][2];

    // ---- Phase 0: read B all + A m0-1; issue (t+1).B1 -> other buf ----
#pragma unroll
    for (int n = 0; n < 4; ++n) {
      bfr[n][0] = *(const short8_t*)&lds[cb + boff0 + n * 1024];
      bfr[n][1] = *(const short8_t*)&lds[cb + boff1 + n * 1024];
    }
#pragma unroll
    for (int ii = 0; ii < 2; ++ii) {
      af01[ii][0] = *(const short8_t*)&lds[cb + aoff0 + ii * 1024];
      af01[ii][1] = *(const short8_t*)&lds[cb + aoff1 + ii * 1024];
    }
    if (kt + 1 < NT) STAGE_B(1, kt + 1, cur ^ 1);
    __builtin_amdgcn_s_barrier();
    __builtin_amdgcn_s_setprio(1);
#pragma unroll
    for (int ks = 0; ks < 2; ++ks)
#pragma unroll
      for (int ii = 0; ii < 2; ++ii)
#pragma unroll
        for (int n = 0; n < 4; ++n)
          acc[ii][n] = __builtin_amdgcn_mfma_f32_16x16x32_bf16(
              af01[ii][ks], bfr[n][ks], acc[ii][n], 0, 0, 0);
    __builtin_amdgcn_s_setprio(0);
    __builtin_amdgcn_s_barrier();

    // ---- Phase 1: read A m2-3; issue (t+2).B0 -> cur buf (B reads of
    // buf[cur] completed by P0's MFMA wait + barrier in every wave) ----
#pragma unroll
    for (int ii = 0; ii < 2; ++ii) {
      af23[ii][0] = *(const short8_t*)&lds[cb + aoff0 + (2 + ii) * 1024];
      af23[ii][1] = *(const short8_t*)&lds[cb + aoff1 + (2 + ii) * 1024];
    }
    if (kt + 2 < NT) STAGE_B(0, kt + 2, cur);
    __builtin_amdgcn_s_barrier();
    __builtin_amdgcn_s_setprio(1);
#pragma unroll
    for (int ks = 0; ks < 2; ++ks)
#pragma unroll
      for (int ii = 0; ii < 2; ++ii)
#pragma unroll
        for (int n = 0; n < 4; ++n)
          acc[2 + ii][n] = __builtin_amdgcn_mfma_f32_16x16x32_bf16(
              af23[ii][ks], bfr[n][ks], acc[2 + ii][n], 0, 0, 0);
    __builtin_amdgcn_s_setprio(0);
    __builtin_amdgcn_s_barrier();

    // ---- Phase 2: read A m4-7; MFMA m4-5; drain lgkm so ALL buf[cur]
    // reads are complete before P3's A-granule overwrite issue ----
#pragma unroll
    for (int ii = 0; ii < 2; ++ii) {
      af45[ii][0] = *(const short8_t*)&lds[cb + aoff0 + (4 + ii) * 1024];
      af45[ii][1] = *(const short8_t*)&lds[cb + aoff1 + (4 + ii) * 1024];
      af67[ii][0] = *(const short8_t*)&lds[cb + aoff0 + (6 + ii) * 1024];
      af67[ii][1] = *(const short8_t*)&lds[cb + aoff1 + (6 + ii) * 1024];
    }
    __builtin_amdgcn_s_barrier();
    __builtin_amdgcn_s_setprio(1);
#pragma unroll
    for (int ks = 0; ks < 2; ++ks)
#pragma unroll
      for (int ii = 0; ii < 2; ++ii)
#pragma unroll
        for (int n = 0; n < 4; ++n)
          acc[4 + ii][n] = __builtin_amdgcn_mfma_f32_16x16x32_bf16(
              af45[ii][ks], bfr[n][ks], acc[4 + ii][n], 0, 0, 0);
    __builtin_amdgcn_s_setprio(0);
    asm volatile("s_waitcnt lgkmcnt(0)" ::: "memory");
    __builtin_amdgcn_s_barrier();

    // ---- Phase 3: issue (t+2).A0,A1 -> cur buf; MFMA m6-7; counted
    // vmcnt: 3 granules (6 loads) younger than tile t+1's last granule ----
    if (kt + 2 < NT) { STAGE_A(0, kt + 2, cur); STAGE_A(1, kt + 2, cur); }
    __builtin_amdgcn_s_barrier();
    __builtin_amdgcn_s_setprio(1);
#pragma unroll
    for (int ks = 0; ks < 2; ++ks)
#pragma unroll
      for (int ii = 0; ii < 2; ++ii)
#pragma unroll
        for (int n = 0; n < 4; ++n)
          acc[6 + ii][n] = __builtin_amdgcn_mfma_f32_16x16x32_bf16(
              af67[ii][ks], bfr[n][ks], acc[6 + ii][n], 0, 0, 0);
    __builtin_amdgcn_s_setprio(0);
    if (kt + 2 < NT)
      asm volatile("s_waitcnt vmcnt(6)" ::: "memory");
    else if (kt + 1 < NT)
      asm volatile("s_waitcnt vmcnt(0)" ::: "memory");
    __builtin_amdgcn_s_barrier();
    // Pin the tile boundary: next iteration's ds_reads must not hoist
    // above {my vmcnt; barrier} (cross-wave landing guarantee).
    __builtin_amdgcn_sched_barrier(0);
  }

#undef STAGE_B
#undef STAGE_A
#undef GLD

  // Epilogue: C/D layout col=lane&15, row=(lane>>4)*4+reg. Fuse bias+relu.
#pragma unroll
  for (int n = 0; n < 4; ++n) {
    int col = col0 + wn * 64 + n * 16 + mrow;
    float bcol = bias[col];
#pragma unroll
    for (int i = 0; i < 8; ++i) {
#pragma unroll
      for (int r = 0; r < 4; ++r) {
        int row = row0 + wm * 128 + i * 16 + half * 4 + r;
        float v = acc[i][n][r] + bcol;
        C[(size_t)row * GN + col] = v > 0.f ? v : 0.f;
      }
    }
  }
}

// ---------------------------------------------------------------------------
extern "C" void kernel_launch(void* const* d_in, const int* in_sizes, int n_in,
                              void* d_out, int out_size, void* d_ws, size_t ws_size,
                              hipStream_t stream) {
  const float* x  = (const float*)d_in[0];
  const float* c0 = (const float*)d_in[1];
  const float* c1 = (const float*)d_in[2];
  const float* c2 = (const float*)d_in[3];
  const float* c3 = (const float*)d_in[4];
  const float* b  = (const float*)d_in[5];
  float* out = (float*)d_out;

  // Workspace layout: [xb 32MB][Mt 32MB][G01 256KB][G23t 256KB]
  unsigned short* xb = (unsigned short*)d_ws;
  unsigned short* Mt = (unsigned short*)((char*)d_ws + (32u << 20));
  float* G01 = (float*)((char*)d_ws + (64u << 20));
  float* G23t = G01 + 65536;

  static bool lds_configured = false;
  if (!lds_configured) {
    (void)hipFuncSetAttribute((const void*)gemm_bias_relu,
                              hipFuncAttributeMaxDynamicSharedMemorySize,
                              131072);
    lds_configured = true;
  }

  prep_kernel<<<512, 256, 0, stream>>>(c0, c1, c2, c3, G01, G23t);
  mt_convert<<<1024 + (GM * GK) / (256 * 8), 256, 0, stream>>>(
      G01, G23t, Mt, x, xb);
  gemm_bias_relu<<<(GM / 256) * (GN / 256), 512, 131072, stream>>>(
      xb, Mt, b, out);
}

// Round 2
// 247.049 us; speedup vs baseline: 1.0404x; 1.0404x over previous
//
#include <hip/hip_runtime.h>
#include <hip/hip_bf16.h>
#include <cstdint>
#include <cstddef>

// TT-dense: y = relu(x @ M + b)
// x: [4096,4096] f32, M: TT(cores r=1,16,16,16,1, dims 8^4 x 8^4), out f32.
//
// Route: materialize M^T in bf16, convert x to bf16, one 4096^3 bf16 MFMA
// GEMM with fused bias+relu.
// History: R2 swizzle kills conflicts; R4 BK=64; R5 full-rate swizzle -> 0
//   conflicts, ~160us GEMM (m97 ceiling); R7 split pre-work -> 268.7us.
// R8: 256^2 8-wave double-buffered schedule, granule prefetch, counted
//   vmcnt(6), 8 barriers/K-tile -> GEMM 135us (1.02 PF), MfmaUtil 43.6%,
//   conflicts 0. Cycle model: 768 LDS + 620 MFMA cyc/tile run SERIAL
//   (1422 observed) because every phase is barrier-bracketed.
// R9: barrier minimization. Only 3 hazards exist per K-tile:
//   (a) B-region overwrite needs all waves' B-reads done  -> bar after MFMA m0-1
//   (b) A-region overwrite needs all waves' A-reads done  -> lgkmcnt(0)+bar after m4-5
//   (c) next tile's reads need staged granules landed      -> vmcnt(6)+bar at tile end
//   8 -> 3 barriers/tile; spans between them let ds_read drain under MFMA
//   issue (cap ~77% MfmaUtil). sched_barrier(0) after each barrier pins
//   memory-op motion across sync points.

#define GM 4096
#define GN 4096
#define GK 4096
#define NT (GK / 64)

typedef __attribute__((ext_vector_type(8))) short short8_t;
typedef __attribute__((ext_vector_type(4))) float float4_t;

__device__ __forceinline__ unsigned short f2bf(float f) {
  union { float f; uint32_t u; } v; v.f = f;
  uint32_t u = v.u;
  uint32_t r = (u + 0x7fffu + ((u >> 16) & 1u)) >> 16;  // RNE
  return (unsigned short)r;
}

// ---------------------------------------------------------------------------
// Kernel 1 (512 blocks, ~4us): merge core pairs.
// G01[a01][b01][r2] = sum_r1 core0[0,a0,b0,r1] * core1[r1,a1,b1,r2]
// G23t[r2][b23][a23] = sum_r3 core2[r2,a2,b2,r3] * core3[r3,a3,b3,0]
// ---------------------------------------------------------------------------
__global__ __launch_bounds__(256) void prep_kernel(
    const float* __restrict__ c0, const float* __restrict__ c1,
    const float* __restrict__ c2, const float* __restrict__ c3,
    float* __restrict__ G01, float* __restrict__ G23t) {
  int idx = blockIdx.x * 256 + threadIdx.x;  // 0..131071
  if (idx < 65536) {
    int r2 = idx & 15;
    int b01 = (idx >> 4) & 63;
    int a01 = idx >> 10;
    int a0 = a01 >> 3, a1 = a01 & 7, b0 = b01 >> 3, b1 = b01 & 7;
    float s = 0.f;
#pragma unroll
    for (int r1 = 0; r1 < 16; ++r1)
      s += c0[(a0 * 8 + b0) * 16 + r1] * c1[((r1 * 8 + a1) * 8 + b1) * 16 + r2];
    G01[idx] = s;
  } else {
    int t = idx - 65536;  // t = r2*4096 + b23*64 + a23
    int a23 = t & 63;
    int b23 = (t >> 6) & 63;
    int r2 = t >> 12;
    int a2 = a23 >> 3, a3 = a23 & 7, b2 = b23 >> 3, b3 = b23 & 7;
    float s = 0.f;
#pragma unroll
    for (int r3 = 0; r3 < 16; ++r3)
      s += c2[((r2 * 8 + a2) * 8 + b2) * 16 + r3] * c3[(r3 * 8 + a3) * 8 + b3];
    G23t[t] = s;
  }
}

// ---------------------------------------------------------------------------
// Kernel 2 (fused, mutually independent halves):
//  blocks [0,1024): Mt[n][k] = sum_r2 G01[a01][b01][r2] * G23t[r2][b23][a23]
//  blocks [1024, 9216): x f32 -> bf16 RNE, 8 elems/thread.
// ---------------------------------------------------------------------------
__global__ __launch_bounds__(256) void mt_convert(
    const float* __restrict__ G01, const float* __restrict__ G23t,
    unsigned short* __restrict__ Mt,
    const float* __restrict__ x, unsigned short* __restrict__ xb) {
  int bid = blockIdx.x;
  int tid = threadIdx.x;
  if (bid < 1024) {
    int a01 = bid >> 4;
    int g = bid & 15;  // b01 = g*4 + j

    float acc[4][16];
#pragma unroll
    for (int j = 0; j < 4; ++j)
#pragma unroll
      for (int i = 0; i < 16; ++i) acc[j][i] = 0.f;

    for (int r2 = 0; r2 < 16; ++r2) {
      float gv[4];
#pragma unroll
      for (int j = 0; j < 4; ++j)
        gv[j] = G01[(a01 * 64 + g * 4 + j) * 16 + r2];  // block-uniform
      const float* src = G23t + r2 * 4096 + tid * 16;   // 64B contiguous/lane
      float4_t v0 = *(const float4_t*)(src);
      float4_t v1 = *(const float4_t*)(src + 4);
      float4_t v2 = *(const float4_t*)(src + 8);
      float4_t v3 = *(const float4_t*)(src + 12);
#pragma unroll
      for (int j = 0; j < 4; ++j) {
#pragma unroll
        for (int l = 0; l < 4; ++l) {
          acc[j][l]      += gv[j] * v0[l];
          acc[j][4 + l]  += gv[j] * v1[l];
          acc[j][8 + l]  += gv[j] * v2[l];
          acc[j][12 + l] += gv[j] * v3[l];
        }
      }
    }

    int b23 = tid >> 2;
    int a23base = (tid & 3) * 16;
#pragma unroll
    for (int j = 0; j < 4; ++j) {
      short8_t o0, o1;
#pragma unroll
      for (int i = 0; i < 8; ++i) {
        o0[i] = (short)f2bf(acc[j][i]);
        o1[i] = (short)f2bf(acc[j][8 + i]);
      }
      size_t base = (size_t)((g * 4 + j) * 64 + b23) * GK + a01 * 64 + a23base;
      *(short8_t*)(Mt + base) = o0;
      *(short8_t*)(Mt + base + 8) = o1;
    }
  } else {
    int i = ((bid - 1024) * 256 + tid) * 8;
    float4_t a = *(const float4_t*)(x + i);
    float4_t b = *(const float4_t*)(x + i + 4);
    short8_t o;
    o[0] = (short)f2bf(a[0]); o[1] = (short)f2bf(a[1]);
    o[2] = (short)f2bf(a[2]); o[3] = (short)f2bf(a[3]);
    o[4] = (short)f2bf(b[0]); o[5] = (short)f2bf(b[1]);
    o[6] = (short)f2bf(b[2]); o[7] = (short)f2bf(b[3]);
    *(short8_t*)(xb + i) = o;
  }
}

// ---------------------------------------------------------------------------
// Kernel 3: C = relu(A @ Bt^T + bias). A:[M][K] bf16, Bt:[N][K] bf16.
//
// 256x256 tile, BK=64, 8 waves (2M x 4N), 512 threads, 128 KiB LDS
// (2 buffers x (A 32KB + B 32KB)). 3 sync points per K-tile:
//   S0: ds_read B(8)+A m0-1(4); issue (t+1).B1 -> other buf; MFMA m0-1.
//       bar#1  (all waves consumed B via MFMA -> B-region of cur free)
//   S1: issue (t+2).B0 -> cur; ds_read A m2-7(12); MFMA m2-5; lgkmcnt(0).
//       bar#2  (all waves' A reads complete -> A-region of cur free)
//   S2: issue (t+2).A0,A1 -> cur; MFMA m6-7; vmcnt(6).
//       bar#3  (tile t+1 fully landed; 6 younger loads stay in flight)
// vmcnt(6) = loads issued after (t+1).B1: B0+A0+A1 of t+2 = 6. Never 0 in
// the main loop (tail kt=NT-2: vmcnt(0)). sched_barrier(0) after each
// barrier prevents compiler motion of ds_read/global_load_lds across sync.
//
// LDS rotation swizzle (R5, 0 conflicts): row r chunk of k-half h stored at
// pos p=(h+r)&7; staging keeps lane-linear LDS dest and permutes the global
// source k-offset. Frag reads: one base/matrix, ks=1 = ^32, frag m = +m*1024.
//
// XCD swizzle: 256 blocks = 1/CU; each XCD gets a 4x8 region of the 16x16
// tile grid (bijective, 256%8==0).
// ---------------------------------------------------------------------------
__global__ __launch_bounds__(512, 2) void gemm_bias_relu(
    const unsigned short* __restrict__ A, const unsigned short* __restrict__ Bt,
    const float* __restrict__ bias, float* __restrict__ C) {
  extern __shared__ __align__(16) unsigned short lds[];

  const int tid = threadIdx.x;
  const int bswz = blockIdx.x;
  const int xcd = bswz & 7, li = bswz >> 3;
  const int row0 = ((xcd >> 1) * 4 + (li >> 3)) * 256;
  const int col0 = ((xcd & 1) * 8 + (li & 7)) * 256;
  const int wave = tid >> 6, lane = tid & 63;
  const int wm = wave >> 2, wn = wave & 3;
  const int half = lane >> 4, mrow = lane & 15;

  // Staging invariants: chunk c = q*512+tid; r=c>>3, p=c&7, h=(p-r)&7.
  const int r0 = tid >> 3, p0 = tid & 7, h0 = (p0 - r0) & 7;
  const unsigned short* Abase = A + (size_t)(row0 + r0) * GK + h0 * 8;
  const unsigned short* Bbase = Bt + (size_t)(col0 + r0) * GK + h0 * 8;
  const int dA = r0 * 64 + p0 * 8;   // shorts; wave-linear: = tid*16 bytes
  const int dB = dA + 16384;

#define GLD(SRC, DST)                                                  \
  __builtin_amdgcn_global_load_lds(                                    \
      (const __attribute__((address_space(1))) void*)(SRC),            \
      (__attribute__((address_space(3))) void*)(lds + (DST)), 16, 0, 0)
#define STAGE_A(G, KT, BUF)                                            \
  do {                                                                 \
    const unsigned short* s_ = Abase + (size_t)(G) * 128 * GK + (KT) * 64; \
    GLD(s_, (BUF) * 32768 + (G) * 8192 + dA);                          \
    GLD(s_ + (size_t)64 * GK, (BUF) * 32768 + (G) * 8192 + dA + 4096); \
  } while (0)
#define STAGE_B(G, KT, BUF)                                            \
  do {                                                                 \
    const unsigned short* s_ = Bbase + (size_t)(G) * 128 * GK + (KT) * 64; \
    GLD(s_, (BUF) * 32768 + (G) * 8192 + dB);                          \
    GLD(s_ + (size_t)64 * GK, (BUF) * 32768 + (G) * 8192 + dB + 4096); \
  } while (0)

  // Fragment read offsets (shorts). r%8 is m-invariant -> single base,
  // ks=1 flips rotation bit2 -> ^32 shorts; frag m adds m*1024.
  const int arow = wm * 128 + mrow;
  const int aoff0 = arow * 64 + ((half + arow) & 7) * 8;
  const int aoff1 = aoff0 ^ 32;
  const int brow = wn * 64 + mrow;
  const int boff0 = 16384 + brow * 64 + ((half + brow) & 7) * 8;
  const int boff1 = boff0 ^ 32;

  float4_t acc[8][4];
#pragma unroll
  for (int i = 0; i < 8; ++i)
#pragma unroll
    for (int n = 0; n < 4; ++n) acc[i][n] = (float4_t){0.f, 0.f, 0.f, 0.f};

  // Prologue: tile0 complete -> buf0; tile1 {B0,A0,A1} -> buf1 (B1 comes at
  // tile0.S0). vmcnt(6): tile0's 8 loads landed, 3 granules outstanding.
  STAGE_A(0, 0, 0); STAGE_A(1, 0, 0); STAGE_B(0, 0, 0); STAGE_B(1, 0, 0);
  STAGE_B(0, 1, 1); STAGE_A(0, 1, 1); STAGE_A(1, 1, 1);
  asm volatile("s_waitcnt vmcnt(6)" ::: "memory");
  __builtin_amdgcn_s_barrier();
  __builtin_amdgcn_sched_barrier(0);

#pragma unroll 2
  for (int kt = 0; kt < NT; ++kt) {
    const int cur = kt & 1;
    const int cb = cur * 32768;

    short8_t bfr[4][2], af01[2][2], af23[2][2], af45[2][2], af67[2][2];

    // ---- Span S0: read B all + A m0-1; issue (t+1).B1 -> other buf;
    // MFMA m0-1 (consumes every B read -> completion proof for bar#1) ----
#pragma unroll
    for (int n = 0; n < 4; ++n) {
      bfr[n][0] = *(const short8_t*)&lds[cb + boff0 + n * 1024];
      bfr[n][1] = *(const short8_t*)&lds[cb + boff1 + n * 1024];
    }
#pragma unroll
    for (int ii = 0; ii < 2; ++ii) {
      af01[ii][0] = *(const short8_t*)&lds[cb + aoff0 + ii * 1024];
      af01[ii][1] = *(const short8_t*)&lds[cb + aoff1 + ii * 1024];
    }
    if (kt + 1 < NT) STAGE_B(1, kt + 1, cur ^ 1);
    __builtin_amdgcn_s_setprio(1);
#pragma unroll
    for (int ks = 0; ks < 2; ++ks)
#pragma unroll
      for (int ii = 0; ii < 2; ++ii)
#pragma unroll
        for (int n = 0; n < 4; ++n)
          acc[ii][n] = __builtin_amdgcn_mfma_f32_16x16x32_bf16(
              af01[ii][ks], bfr[n][ks], acc[ii][n], 0, 0, 0);
    __builtin_amdgcn_s_setprio(0);
    __builtin_amdgcn_s_barrier();           // bar#1: B-region of cur free
    __builtin_amdgcn_sched_barrier(0);

    // ---- Span S1: issue (t+2).B0 -> cur; read A m2-7; MFMA m2-5;
    // drain lgkm so ALL of this wave's A reads are complete at bar#2 ----
    if (kt + 2 < NT) STAGE_B(0, kt + 2, cur);
#pragma unroll
    for (int ii = 0; ii < 2; ++ii) {
      af23[ii][0] = *(const short8_t*)&lds[cb + aoff0 + (2 + ii) * 1024];
      af23[ii][1] = *(const short8_t*)&lds[cb + aoff1 + (2 + ii) * 1024];
    }
#pragma unroll
    for (int ii = 0; ii < 2; ++ii) {
      af45[ii][0] = *(const short8_t*)&lds[cb + aoff0 + (4 + ii) * 1024];
      af45[ii][1] = *(const short8_t*)&lds[cb + aoff1 + (4 + ii) * 1024];
      af67[ii][0] = *(const short8_t*)&lds[cb + aoff0 + (6 + ii) * 1024];
      af67[ii][1] = *(const short8_t*)&lds[cb + aoff1 + (6 + ii) * 1024];
    }
    __builtin_amdgcn_s_setprio(1);
#pragma unroll
    for (int ks = 0; ks < 2; ++ks)
#pragma unroll
      for (int ii = 0; ii < 2; ++ii)
#pragma unroll
        for (int n = 0; n < 4; ++n)
          acc[2 + ii][n] = __builtin_amdgcn_mfma_f32_16x16x32_bf16(
              af23[ii][ks], bfr[n][ks], acc[2 + ii][n], 0, 0, 0);
#pragma unroll
    for (int ks = 0; ks < 2; ++ks)
#pragma unroll
      for (int ii = 0; ii < 2; ++ii)
#pragma unroll
        for (int n = 0; n < 4; ++n)
          acc[4 + ii][n] = __builtin_amdgcn_mfma_f32_16x16x32_bf16(
              af45[ii][ks], bfr[n][ks], acc[4 + ii][n], 0, 0, 0);
    __builtin_amdgcn_s_setprio(0);
    asm volatile("s_waitcnt lgkmcnt(0)" ::: "memory");
    __builtin_amdgcn_s_barrier();           // bar#2: A-region of cur free
    __builtin_amdgcn_sched_barrier(0);

    // ---- Span S2: issue (t+2).A0,A1 -> cur; MFMA m6-7; counted vmcnt:
    // 6 loads (B0,A0,A1 of t+2) younger than (t+1).B1 stay in flight ----
    if (kt + 2 < NT) { STAGE_A(0, kt + 2, cur); STAGE_A(1, kt + 2, cur); }
    __builtin_amdgcn_s_setprio(1);
#pragma unroll
    for (int ks = 0; ks < 2; ++ks)
#pragma unroll
      for (int ii = 0; ii < 2; ++ii)
#pragma unroll
        for (int n = 0; n < 4; ++n)
          acc[6 + ii][n] = __builtin_amdgcn_mfma_f32_16x16x32_bf16(
              af67[ii][ks], bfr[n][ks], acc[6 + ii][n], 0, 0, 0);
    __builtin_amdgcn_s_setprio(0);
    if (kt + 2 < NT)
      asm volatile("s_waitcnt vmcnt(6)" ::: "memory");
    else if (kt + 1 < NT)
      asm volatile("s_waitcnt vmcnt(0)" ::: "memory");
    __builtin_amdgcn_s_barrier();           // bar#3: tile t+1 landed
    __builtin_amdgcn_sched_barrier(0);
  }

#undef STAGE_B
#undef STAGE_A
#undef GLD

  // Epilogue: C/D layout col=lane&15, row=(lane>>4)*4+reg. Fuse bias+relu.
#pragma unroll
  for (int n = 0; n < 4; ++n) {
    int col = col0 + wn * 64 + n * 16 + mrow;
    float bcol = bias[col];
#pragma unroll
    for (int i = 0; i < 8; ++i) {
#pragma unroll
      for (int r = 0; r < 4; ++r) {
        int row = row0 + wm * 128 + i * 16 + half * 4 + r;
        float v = acc[i][n][r] + bcol;
        C[(size_t)row * GN + col] = v > 0.f ? v : 0.f;
      }
    }
  }
}

// ---------------------------------------------------------------------------
extern "C" void kernel_launch(void* const* d_in, const int* in_sizes, int n_in,
                              void* d_out, int out_size, void* d_ws, size_t ws_size,
                              hipStream_t stream) {
  const float* x  = (const float*)d_in[0];
  const float* c0 = (const float*)d_in[1];
  const float* c1 = (const float*)d_in[2];
  const float* c2 = (const float*)d_in[3];
  const float* c3 = (const float*)d_in[4];
  const float* b  = (const float*)d_in[5];
  float* out = (float*)d_out;

  // Workspace layout: [xb 32MB][Mt 32MB][G01 256KB][G23t 256KB]
  unsigned short* xb = (unsigned short*)d_ws;
  unsigned short* Mt = (unsigned short*)((char*)d_ws + (32u << 20));
  float* G01 = (float*)((char*)d_ws + (64u << 20));
  float* G23t = G01 + 65536;

  static bool lds_configured = false;
  if (!lds_configured) {
    (void)hipFuncSetAttribute((const void*)gemm_bias_relu,
                              hipFuncAttributeMaxDynamicSharedMemorySize,
                              131072);
    lds_configured = true;
  }

  prep_kernel<<<512, 256, 0, stream>>>(c0, c1, c2, c3, G01, G23t);
  mt_convert<<<1024 + (GM * GK) / (256 * 8), 256, 0, stream>>>(
      G01, G23t, Mt, x, xb);
  gemm_bias_relu<<<(GM / 256) * (GN / 256), 512, 131072, stream>>>(
      xb, Mt, b, out);
}